// Round 1
// baseline (166.988 us; speedup 1.0000x reference)
//
#include <hip/hip_runtime.h>
#include <hip/hip_bf16.h>

#define B_   64
#define C_   512
#define N_   1024
#define NROW (B_ * C_)        // 32768 rows per tensor
#define BM   128
#define BK   64
#define NJOBS 36              // 10 tt + 10 ss + 16 ts tiles per batch
#define NBLK (B_ * NJOBS)     // 2304 blocks

typedef __attribute__((ext_vector_type(8))) short bf16x8;
typedef __attribute__((ext_vector_type(4))) float f32x4;

__device__ __forceinline__ ushort f2bf(float x) {
  union { float f; uint u; } c; c.f = x;
  uint u = c.u;
  u += 0x7FFFu + ((u >> 16) & 1u);   // round-to-nearest-even
  return (ushort)(u >> 16);
}

__device__ __forceinline__ float wave_reduce(float v) {
  #pragma unroll
  for (int o = 32; o > 0; o >>= 1) v += __shfl_down(v, o, 64);
  return v;
}

// ---------------- Kernel 1 (fast path): fused L2-normalize + bf16 convert ---
// one block (256 thr) per row of 1024 floats
__global__ __launch_bounds__(256) void rownorm_bf16(
    const float* __restrict__ fmt, const float* __restrict__ fms,
    ushort* __restrict__ nt, ushort* __restrict__ ns) {
  const int bid = blockIdx.x;
  const int arr = bid >> 15;            // 0 -> t, 1 -> s
  const int row = bid & (NROW - 1);
  const float* src = arr ? fms : fmt;
  ushort* dst = arr ? ns : nt;
  const float4* sp = (const float4*)(src + (size_t)row * N_);
  float4 v = sp[threadIdx.x];
  float ss = v.x * v.x + v.y * v.y + v.z * v.z + v.w * v.w;
  ss = wave_reduce(ss);
  __shared__ float red[4];
  const int lane = threadIdx.x & 63, w = threadIdx.x >> 6;
  if (lane == 0) red[w] = ss;
  __syncthreads();
  const float tot = red[0] + red[1] + red[2] + red[3];
  const float inv = 1.0f / fmaxf(sqrtf(tot), 1e-12f);
  ushort4 o;
  o.x = f2bf(v.x * inv); o.y = f2bf(v.y * inv);
  o.z = f2bf(v.z * inv); o.w = f2bf(v.w * inv);
  ((ushort4*)(dst + (size_t)row * N_))[threadIdx.x] = o;
}

// ---------------- Kernel 1 (slow path): inverse norms only ------------------
__global__ __launch_bounds__(256) void rownorm_inv(
    const float* __restrict__ fmt, const float* __restrict__ fms,
    float* __restrict__ invT, float* __restrict__ invS) {
  const int bid = blockIdx.x;
  const int arr = bid >> 15;
  const int row = bid & (NROW - 1);
  const float* src = arr ? fms : fmt;
  const float4* sp = (const float4*)(src + (size_t)row * N_);
  float4 v = sp[threadIdx.x];
  float ss = v.x * v.x + v.y * v.y + v.z * v.z + v.w * v.w;
  ss = wave_reduce(ss);
  __shared__ float red[4];
  const int lane = threadIdx.x & 63, w = threadIdx.x >> 6;
  if (lane == 0) red[w] = ss;
  __syncthreads();
  if (threadIdx.x == 0) {
    const float tot = red[0] + red[1] + red[2] + red[3];
    (arr ? invS : invT)[row] = 1.0f / fmaxf(sqrtf(tot), 1e-12f);
  }
}

// ---------------- Kernel 2: batched gram sum-of-squares ---------------------
// PATH 0: stage bf16 from ws via global_load_lds(16B)
// PATH 1: stage fp32 from inputs, scale by inv norm, convert to bf16
template<int PATH>
__global__ __launch_bounds__(256) void gram_kernel(
    const ushort* __restrict__ nt, const ushort* __restrict__ ns,
    const float*  __restrict__ ft, const float*  __restrict__ fs,
    const float*  __restrict__ invT, const float* __restrict__ invS,
    float* __restrict__ partials)
{
  __shared__ ushort As[BM * BK];
  __shared__ ushort Bs[BM * BK];
  __shared__ float red[4];

  const int tid = threadIdx.x;
  const int orig = blockIdx.x;
  // bijective XCD swizzle: 2304 = 288 * 8 -> XCD x gets batches [x*8, x*8+8)
  const int lin = (orig & 7) * (NBLK / 8) + (orig >> 3);
  const int b = lin / NJOBS;
  const int job = lin - b * NJOBS;

  int gi, gj;
  float wgt;
  int selA, selB;                 // 0 = t, 1 = s
  if (job < 20) {
    const int idx = (job < 10) ? job : job - 10;
    int i = 0, t = idx;
    while (t >= 4 - i) { t -= 4 - i; ++i; }
    gi = i; gj = i + t;
    wgt = (gi == gj) ? 1.0f : 2.0f;
    selA = selB = (job < 10) ? 0 : 1;
  } else {
    const int idx = job - 20;
    gi = idx >> 2; gj = idx & 3;
    wgt = -2.0f;
    selA = 0; selB = 1;
  }

  const size_t baseA = (size_t)b * C_ * N_ + (size_t)gi * BM * N_;
  const size_t baseB = (size_t)b * C_ * N_ + (size_t)gj * BM * N_;
  const ushort* gA = (selA ? ns : nt) + baseA;
  const ushort* gB = (selB ? ns : nt) + baseB;
  const float*  fA = (selA ? fs : ft) + baseA;
  const float*  fB = (selB ? fs : ft) + baseB;
  const float*  iA = (selA ? invS : invT) + (size_t)b * C_ + gi * BM;
  const float*  iB = (selB ? invS : invT) + (size_t)b * C_ + gj * BM;

  const int lane = tid & 63;
  const int wave = tid >> 6;
  const int wr = wave >> 1, wc = wave & 1;   // 2x2 waves -> 64x64 each
  const int fr = lane & 15;                  // fragment row
  const int kg = lane >> 4;                  // k-group (8 bf16 each)

  f32x4 acc[4][4];
  #pragma unroll
  for (int m = 0; m < 4; ++m)
    #pragma unroll
    for (int n = 0; n < 4; ++n)
      acc[m][n] = (f32x4)0.0f;

  for (int kt = 0; kt < N_ / BK; ++kt) {
    const int k0 = kt * BK;
    __syncthreads();   // previous MFMA fragment reads complete before overwrite
    if (PATH == 0) {
      #pragma unroll
      for (int r = 0; r < 4; ++r) {
        const int chunk = r * 256 + tid;
        const int row = chunk >> 3, cc = (chunk & 7) * 8;
        __builtin_amdgcn_global_load_lds(
            (const __attribute__((address_space(1))) void*)(gA + (size_t)row * N_ + k0 + cc),
            (__attribute__((address_space(3))) void*)(As + chunk * 8), 16, 0, 0);
      }
      #pragma unroll
      for (int r = 0; r < 4; ++r) {
        const int chunk = r * 256 + tid;
        const int row = chunk >> 3, cc = (chunk & 7) * 8;
        __builtin_amdgcn_global_load_lds(
            (const __attribute__((address_space(1))) void*)(gB + (size_t)row * N_ + k0 + cc),
            (__attribute__((address_space(3))) void*)(Bs + chunk * 8), 16, 0, 0);
      }
    } else {
      #pragma unroll
      for (int r = 0; r < 8; ++r) {
        const int chunk = r * 256 + tid;
        const int row = chunk >> 4, cc = (chunk & 15) * 4;
        const float4 v = *(const float4*)(fA + (size_t)row * N_ + k0 + cc);
        const float inv = iA[row];
        ushort4 o;
        o.x = f2bf(v.x * inv); o.y = f2bf(v.y * inv);
        o.z = f2bf(v.z * inv); o.w = f2bf(v.w * inv);
        *(ushort4*)(As + row * BK + cc) = o;
      }
      #pragma unroll
      for (int r = 0; r < 8; ++r) {
        const int chunk = r * 256 + tid;
        const int row = chunk >> 4, cc = (chunk & 15) * 4;
        const float4 v = *(const float4*)(fB + (size_t)row * N_ + k0 + cc);
        const float inv = iB[row];
        ushort4 o;
        o.x = f2bf(v.x * inv); o.y = f2bf(v.y * inv);
        o.z = f2bf(v.z * inv); o.w = f2bf(v.w * inv);
        *(ushort4*)(Bs + row * BK + cc) = o;
      }
    }
    __syncthreads();   // staging complete (compiler drains vmcnt before barrier)

    #pragma unroll
    for (int ko = 0; ko < BK; ko += 32) {
      bf16x8 av[4], bv[4];
      #pragma unroll
      for (int m = 0; m < 4; ++m)
        av[m] = *(const bf16x8*)(As + (wr * 64 + m * 16 + fr) * BK + ko + kg * 8);
      #pragma unroll
      for (int n = 0; n < 4; ++n)
        bv[n] = *(const bf16x8*)(Bs + (wc * 64 + n * 16 + fr) * BK + ko + kg * 8);
      #pragma unroll
      for (int m = 0; m < 4; ++m)
        #pragma unroll
        for (int n = 0; n < 4; ++n)
          acc[m][n] = __builtin_amdgcn_mfma_f32_16x16x32_bf16(av[m], bv[n], acc[m][n], 0, 0, 0);
    }
  }

  // epilogue: weighted sum of squares (layout-independent)
  float p = 0.0f;
  #pragma unroll
  for (int m = 0; m < 4; ++m)
    #pragma unroll
    for (int n = 0; n < 4; ++n)
      #pragma unroll
      for (int j = 0; j < 4; ++j)
        p += acc[m][n][j] * acc[m][n][j];
  p *= wgt;
  p = wave_reduce(p);
  if (lane == 0) red[wave] = p;
  __syncthreads();
  if (tid == 0) partials[orig] = red[0] + red[1] + red[2] + red[3];
}

// ---------------- Kernel 3: final deterministic reduce ----------------------
__global__ __launch_bounds__(256) void reduce_partials(
    const float* __restrict__ partials, float* __restrict__ out) {
  float v = 0.0f;
  for (int i = threadIdx.x; i < NBLK; i += 256) v += partials[i];
  v = wave_reduce(v);
  __shared__ float red[4];
  const int lane = threadIdx.x & 63, w = threadIdx.x >> 6;
  if (lane == 0) red[w] = v;
  __syncthreads();
  if (threadIdx.x == 0)
    out[0] = (red[0] + red[1] + red[2] + red[3]) * (1.0f / 16777216.0f);
}

extern "C" void kernel_launch(void* const* d_in, const int* in_sizes, int n_in,
                              void* d_out, int out_size, void* d_ws, size_t ws_size,
                              hipStream_t stream) {
  const float* fm_s = (const float*)d_in[0];
  const float* fm_t = (const float*)d_in[1];
  float* out = (float*)d_out;

  const size_t bf16_elems = (size_t)B_ * C_ * N_;          // per tensor
  const size_t need_fast = 2 * bf16_elems * sizeof(ushort) // normalized bf16
                         + (size_t)NBLK * sizeof(float);   // partials

  if (ws_size >= need_fast) {
    ushort* nt = (ushort*)d_ws;
    ushort* ns = nt + bf16_elems;
    float* partials = (float*)((char*)d_ws + 2 * bf16_elems * sizeof(ushort));
    rownorm_bf16<<<2 * NROW / 1, 256, 0, stream>>>(fm_t, fm_s, nt, ns);
    gram_kernel<0><<<NBLK, 256, 0, stream>>>(nt, ns, nullptr, nullptr,
                                             nullptr, nullptr, partials);
    reduce_partials<<<1, 256, 0, stream>>>(partials, out);
  } else {
    float* invT = (float*)d_ws;
    float* invS = invT + NROW;
    float* partials = invS + NROW;
    rownorm_inv<<<2 * NROW, 256, 0, stream>>>(fm_t, fm_s, invT, invS);
    gram_kernel<1><<<NBLK, 256, 0, stream>>>(nullptr, nullptr, fm_t, fm_s,
                                             invT, invS, partials);
    reduce_partials<<<1, 256, 0, stream>>>(partials, out);
  }
}

// Round 2
// 112.466 us; speedup vs baseline: 1.4848x; 1.4848x over previous
//
#include <hip/hip_runtime.h>
#include <hip/hip_bf16.h>

#define B_   64
#define C_   512
#define N_   1024
#define NROW (B_ * C_)        // 32768 rows per tensor
#define BM   128
#define BK   128              // fp8 K-tile (one 16x16x128 MFMA deep)
#define NJOBS 36              // 10 tt + 10 ss + 16 ts tiles per batch
#define NBLK (B_ * NJOBS)     // 2304 blocks

typedef __attribute__((ext_vector_type(8))) int   i32x8;
typedef __attribute__((ext_vector_type(4))) float f32x4;

__device__ __forceinline__ float wave_reduce(float v) {
  #pragma unroll
  for (int o = 32; o > 0; o >>= 1) v += __shfl_down(v, o, 64);
  return v;
}

// ---------------- Kernel 1: fused L2-normalize + (x16) fp8-e4m3 convert ----
// one block (256 thr) per row of 1024 floats; writes 1024 fp8 bytes
__global__ __launch_bounds__(256) void rownorm_fp8(
    const float* __restrict__ fmt, const float* __restrict__ fms,
    unsigned char* __restrict__ nt, unsigned char* __restrict__ ns) {
  const int bid = blockIdx.x;
  const int arr = bid >> 15;            // 0 -> t, 1 -> s
  const int row = bid & (NROW - 1);
  const float* src = arr ? fms : fmt;
  unsigned char* dst = arr ? ns : nt;
  const float4* sp = (const float4*)(src + (size_t)row * N_);
  float4 v = sp[threadIdx.x];
  float ss = v.x * v.x + v.y * v.y + v.z * v.z + v.w * v.w;
  ss = wave_reduce(ss);
  __shared__ float red[4];
  const int lane = threadIdx.x & 63, w = threadIdx.x >> 6;
  if (lane == 0) red[w] = ss;
  __syncthreads();
  const float tot = red[0] + red[1] + red[2] + red[3];
  // x16 scale keeps values in e4m3 normal range; removed exactly (2^-16) later
  const float inv = 16.0f / fmaxf(sqrtf(tot), 1e-12f);
  int p = __builtin_amdgcn_cvt_pk_fp8_f32(v.x * inv, v.y * inv, 0, false);
  p = __builtin_amdgcn_cvt_pk_fp8_f32(v.z * inv, v.w * inv, p, true);
  ((int*)(dst + (size_t)row * N_))[threadIdx.x] = p;
}

// ---------------- Kernel 2: batched gram sum-of-squares (MX-fp8, K=128) ----
__global__ __launch_bounds__(256) void gram_kernel(
    const unsigned char* __restrict__ nt, const unsigned char* __restrict__ ns,
    float* __restrict__ partials)
{
  __shared__ __align__(64) unsigned char As[BM * BK];
  __shared__ __align__(64) unsigned char Bs[BM * BK];
  __shared__ float red[4];

  const int tid = threadIdx.x;
  const int orig = blockIdx.x;
  // bijective XCD swizzle: 2304 = 288 * 8 -> XCD x gets batches [x*8, x*8+8)
  const int lin = (orig & 7) * (NBLK / 8) + (orig >> 3);
  const int b = lin / NJOBS;
  const int job = lin - b * NJOBS;

  int gi, gj;
  float wgt;
  int selA, selB;                 // 0 = t, 1 = s
  if (job < 20) {
    const int idx = (job < 10) ? job : job - 10;
    int i = 0, t = idx;
    while (t >= 4 - i) { t -= 4 - i; ++i; }
    gi = i; gj = i + t;
    wgt = (gi == gj) ? 1.0f : 2.0f;
    selA = selB = (job < 10) ? 0 : 1;
  } else {
    const int idx = job - 20;
    gi = idx >> 2; gj = idx & 3;
    wgt = -2.0f;
    selA = 0; selB = 1;
  }

  const size_t baseA = (size_t)b * C_ * N_ + (size_t)gi * BM * N_;
  const size_t baseB = (size_t)b * C_ * N_ + (size_t)gj * BM * N_;
  const unsigned char* gA = (selA ? ns : nt) + baseA;
  const unsigned char* gB = (selB ? ns : nt) + baseB;

  const int lane = tid & 63;
  const int wave = tid >> 6;
  const int wr = wave >> 1, wc = wave & 1;   // 2x2 waves -> 64x64 each
  const int fr = lane & 15;                  // fragment row
  const int kg = lane >> 4;                  // k-group (32 fp8 bytes each)

  f32x4 acc[4][4];
  #pragma unroll
  for (int m = 0; m < 4; ++m)
    #pragma unroll
    for (int n = 0; n < 4; ++n)
      acc[m][n] = (f32x4)0.0f;

  for (int kt = 0; kt < N_ / BK; ++kt) {
    const int k0 = kt * BK;
    __syncthreads();   // previous fragment reads complete before overwrite
    // stage A tile: 128 rows x 128 fp8 bytes = 16 KB, 16B chunks
    #pragma unroll
    for (int r = 0; r < 4; ++r) {
      const int chunk = r * 256 + tid;          // [0,1024)
      const int row = chunk >> 3, cb = (chunk & 7) * 16;
      __builtin_amdgcn_global_load_lds(
          (const __attribute__((address_space(1))) void*)(gA + (size_t)row * N_ + k0 + cb),
          (__attribute__((address_space(3))) void*)(As + chunk * 16), 16, 0, 0);
    }
    #pragma unroll
    for (int r = 0; r < 4; ++r) {
      const int chunk = r * 256 + tid;
      const int row = chunk >> 3, cb = (chunk & 7) * 16;
      __builtin_amdgcn_global_load_lds(
          (const __attribute__((address_space(1))) void*)(gB + (size_t)row * N_ + k0 + cb),
          (__attribute__((address_space(3))) void*)(Bs + chunk * 16), 16, 0, 0);
    }
    __syncthreads();   // staging complete (compiler drains vmcnt before barrier)

    i32x8 av[4], bv[4];
    #pragma unroll
    for (int m = 0; m < 4; ++m)
      av[m] = *(const i32x8*)(As + (wr * 64 + m * 16 + fr) * BK + kg * 32);
    #pragma unroll
    for (int n = 0; n < 4; ++n)
      bv[n] = *(const i32x8*)(Bs + (wc * 64 + n * 16 + fr) * BK + kg * 32);
    #pragma unroll
    for (int m = 0; m < 4; ++m)
      #pragma unroll
      for (int n = 0; n < 4; ++n)
        acc[m][n] = __builtin_amdgcn_mfma_scale_f32_16x16x128_f8f6f4(
            av[m], bv[n], acc[m][n],
            0, 0,                 // cbsz = fp8(e4m3), blgp = fp8(e4m3)
            0, 0x7F7F7F7F,        // opsel_a, scale_a (E8M0 127 = 1.0 in all bytes)
            0, 0x7F7F7F7F);       // opsel_b, scale_b
  }

  // epilogue: weighted sum of squares (layout-independent)
  float p = 0.0f;
  #pragma unroll
  for (int m = 0; m < 4; ++m)
    #pragma unroll
    for (int n = 0; n < 4; ++n)
      #pragma unroll
      for (int j = 0; j < 4; ++j)
        p += acc[m][n][j] * acc[m][n][j];
  p *= wgt;
  p = wave_reduce(p);
  if (lane == 0) red[wave] = p;
  __syncthreads();
  if (tid == 0) partials[orig] = red[0] + red[1] + red[2] + red[3];
}

// ---------------- Kernel 3: final deterministic reduce ----------------------
// factor 2^-40 = 1/(B*C*C) * 2^-16 (the x16 input scaling, squared twice)
__global__ __launch_bounds__(256) void reduce_partials(
    const float* __restrict__ partials, float* __restrict__ out) {
  float v = 0.0f;
  for (int i = threadIdx.x; i < NBLK; i += 256) v += partials[i];
  v = wave_reduce(v);
  __shared__ float red[4];
  const int lane = threadIdx.x & 63, w = threadIdx.x >> 6;
  if (lane == 0) red[w] = v;
  __syncthreads();
  if (threadIdx.x == 0)
    out[0] = (red[0] + red[1] + red[2] + red[3]) * (1.0f / 1099511627776.0f);
}

extern "C" void kernel_launch(void* const* d_in, const int* in_sizes, int n_in,
                              void* d_out, int out_size, void* d_ws, size_t ws_size,
                              hipStream_t stream) {
  const float* fm_s = (const float*)d_in[0];
  const float* fm_t = (const float*)d_in[1];
  float* out = (float*)d_out;

  const size_t fp8_elems = (size_t)B_ * C_ * N_;           // per tensor (bytes)
  unsigned char* nt = (unsigned char*)d_ws;
  unsigned char* ns = nt + fp8_elems;
  float* partials = (float*)((char*)d_ws + 2 * fp8_elems);

  rownorm_fp8<<<2 * NROW, 256, 0, stream>>>(fm_t, fm_s, nt, ns);
  gram_kernel<<<NBLK, 256, 0, stream>>>(nt, ns, partials);
  reduce_partials<<<1, 256, 0, stream>>>(partials, out);
}

// Round 3
// 108.321 us; speedup vs baseline: 1.5416x; 1.0383x over previous
//
#include <hip/hip_runtime.h>
#include <hip/hip_bf16.h>

#define B_   64
#define C_   512
#define N_   1024
#define NROW (B_ * C_)        // 32768 rows per tensor
#define BM   128
#define BK   128              // fp8 K-tile (one 16x16x128 MFMA deep)
#define NJOBS 36              // 10 tt + 10 ss + 16 ts tiles per batch
#define NBLK (B_ * NJOBS)     // 2304 blocks

typedef __attribute__((ext_vector_type(8))) int   i32x8;
typedef __attribute__((ext_vector_type(4))) float f32x4;

__device__ __forceinline__ float wave_reduce(float v) {
  #pragma unroll
  for (int o = 32; o > 0; o >>= 1) v += __shfl_down(v, o, 64);
  return v;
}

// ---------------- Kernel 1: fused L2-normalize + (x16) fp8-e4m3 convert ----
// one WAVE per row of 1024 floats: 4 independent 1KB-coalesced loads/lane,
// butterfly shfl reduce (no LDS, no barrier), 4 coalesced 256B stores.
__global__ __launch_bounds__(256) void rownorm_fp8(
    const float* __restrict__ fmt, const float* __restrict__ fms,
    unsigned char* __restrict__ nt, unsigned char* __restrict__ ns) {
  const int gw   = blockIdx.x * 4 + (threadIdx.x >> 6);  // global wave = row id
  const int lane = threadIdx.x & 63;
  const int arr  = gw >> 15;            // 0 -> t, 1 -> s
  const int row  = gw & (NROW - 1);
  const float* src = (arr ? fms : fmt) + (size_t)row * N_;
  unsigned char* dst = (arr ? ns : nt) + (size_t)row * N_;

  float4 v[4];
  #pragma unroll
  for (int j = 0; j < 4; ++j)
    v[j] = *(const float4*)(src + j * 256 + lane * 4);

  float ss = 0.0f;
  #pragma unroll
  for (int j = 0; j < 4; ++j)
    ss += v[j].x * v[j].x + v[j].y * v[j].y + v[j].z * v[j].z + v[j].w * v[j].w;
  #pragma unroll
  for (int o = 1; o < 64; o <<= 1) ss += __shfl_xor(ss, o, 64);

  // x16 scale keeps values in e4m3 normal range; removed exactly (2^-16) later
  const float inv = 16.0f / fmaxf(sqrtf(ss), 1e-12f);
  #pragma unroll
  for (int j = 0; j < 4; ++j) {
    int p = __builtin_amdgcn_cvt_pk_fp8_f32(v[j].x * inv, v[j].y * inv, 0, false);
    p = __builtin_amdgcn_cvt_pk_fp8_f32(v[j].z * inv, v[j].w * inv, p, true);
    ((int*)(dst + j * 256))[lane] = p;
  }
}

// ---------------- Kernel 2: batched gram sum-of-squares (MX-fp8, K=128) ----
__global__ __launch_bounds__(256) void gram_kernel(
    const unsigned char* __restrict__ nt, const unsigned char* __restrict__ ns,
    float* __restrict__ partials)
{
  __shared__ __align__(64) unsigned char As[BM * BK];
  __shared__ __align__(64) unsigned char Bs[BM * BK];
  __shared__ float red[4];

  const int tid = threadIdx.x;
  const int orig = blockIdx.x;
  // bijective XCD swizzle: 2304 = 288 * 8 -> XCD x gets batches [x*8, x*8+8)
  const int lin = (orig & 7) * (NBLK / 8) + (orig >> 3);
  const int b = lin / NJOBS;
  const int job = lin - b * NJOBS;

  int gi, gj;
  float wgt;
  int selA, selB;                 // 0 = t, 1 = s
  if (job < 20) {
    const int idx = (job < 10) ? job : job - 10;
    int i = 0, t = idx;
    while (t >= 4 - i) { t -= 4 - i; ++i; }
    gi = i; gj = i + t;
    wgt = (gi == gj) ? 1.0f : 2.0f;
    selA = selB = (job < 10) ? 0 : 1;
  } else {
    const int idx = job - 20;
    gi = idx >> 2; gj = idx & 3;
    wgt = -2.0f;
    selA = 0; selB = 1;
  }

  const size_t baseA = (size_t)b * C_ * N_ + (size_t)gi * BM * N_;
  const size_t baseB = (size_t)b * C_ * N_ + (size_t)gj * BM * N_;
  const unsigned char* gA = (selA ? ns : nt) + baseA;
  const unsigned char* gB = (selB ? ns : nt) + baseB;

  const int lane = tid & 63;
  const int wave = tid >> 6;
  const int wr = wave >> 1, wc = wave & 1;   // 2x2 waves -> 64x64 each
  const int fr = lane & 15;                  // fragment row
  const int kg = lane >> 4;                  // k-group (32 fp8 bytes each)

  f32x4 acc[4][4];
  #pragma unroll
  for (int m = 0; m < 4; ++m)
    #pragma unroll
    for (int n = 0; n < 4; ++n)
      acc[m][n] = (f32x4)0.0f;

  for (int kt = 0; kt < N_ / BK; ++kt) {
    const int k0 = kt * BK;
    __syncthreads();   // previous fragment reads complete before overwrite
    // stage A tile: 128 rows x 128 fp8 bytes = 16 KB, 16B chunks
    #pragma unroll
    for (int r = 0; r < 4; ++r) {
      const int chunk = r * 256 + tid;          // [0,1024)
      const int row = chunk >> 3, cb = (chunk & 7) * 16;
      __builtin_amdgcn_global_load_lds(
          (const __attribute__((address_space(1))) void*)(gA + (size_t)row * N_ + k0 + cb),
          (__attribute__((address_space(3))) void*)(As + chunk * 16), 16, 0, 0);
    }
    #pragma unroll
    for (int r = 0; r < 4; ++r) {
      const int chunk = r * 256 + tid;
      const int row = chunk >> 3, cb = (chunk & 7) * 16;
      __builtin_amdgcn_global_load_lds(
          (const __attribute__((address_space(1))) void*)(gB + (size_t)row * N_ + k0 + cb),
          (__attribute__((address_space(3))) void*)(Bs + chunk * 16), 16, 0, 0);
    }
    __syncthreads();   // staging complete (compiler drains vmcnt before barrier)

    i32x8 av[4], bv[4];
    #pragma unroll
    for (int m = 0; m < 4; ++m)
      av[m] = *(const i32x8*)(As + (wr * 64 + m * 16 + fr) * BK + kg * 32);
    #pragma unroll
    for (int n = 0; n < 4; ++n)
      bv[n] = *(const i32x8*)(Bs + (wc * 64 + n * 16 + fr) * BK + kg * 32);
    #pragma unroll
    for (int m = 0; m < 4; ++m)
      #pragma unroll
      for (int n = 0; n < 4; ++n)
        acc[m][n] = __builtin_amdgcn_mfma_scale_f32_16x16x128_f8f6f4(
            av[m], bv[n], acc[m][n],
            0, 0,                 // cbsz = fp8(e4m3), blgp = fp8(e4m3)
            0, 0x7F7F7F7F,        // opsel_a, scale_a (E8M0 127 = 1.0 in all bytes)
            0, 0x7F7F7F7F);       // opsel_b, scale_b
  }

  // epilogue: weighted sum of squares (layout-independent)
  float p = 0.0f;
  #pragma unroll
  for (int m = 0; m < 4; ++m)
    #pragma unroll
    for (int n = 0; n < 4; ++n)
      #pragma unroll
      for (int j = 0; j < 4; ++j)
        p += acc[m][n][j] * acc[m][n][j];
  p *= wgt;
  p = wave_reduce(p);
  if (lane == 0) red[wave] = p;
  __syncthreads();
  if (tid == 0) partials[orig] = red[0] + red[1] + red[2] + red[3];
}

// ---------------- Kernel 3: final deterministic reduce ----------------------
// factor 2^-40 = 1/(B*C*C) * 2^-16 (the x16 input scaling, squared twice)
__global__ __launch_bounds__(256) void reduce_partials(
    const float* __restrict__ partials, float* __restrict__ out) {
  float v = 0.0f;
  for (int i = threadIdx.x; i < NBLK; i += 256) v += partials[i];
  v = wave_reduce(v);
  __shared__ float red[4];
  const int lane = threadIdx.x & 63, w = threadIdx.x >> 6;
  if (lane == 0) red[w] = v;
  __syncthreads();
  if (threadIdx.x == 0)
    out[0] = (red[0] + red[1] + red[2] + red[3]) * (1.0f / 1099511627776.0f);
}

extern "C" void kernel_launch(void* const* d_in, const int* in_sizes, int n_in,
                              void* d_out, int out_size, void* d_ws, size_t ws_size,
                              hipStream_t stream) {
  const float* fm_s = (const float*)d_in[0];
  const float* fm_t = (const float*)d_in[1];
  float* out = (float*)d_out;

  const size_t fp8_elems = (size_t)B_ * C_ * N_;           // per tensor (bytes)
  unsigned char* nt = (unsigned char*)d_ws;
  unsigned char* ns = nt + fp8_elems;
  float* partials = (float*)((char*)d_ws + 2 * fp8_elems);

  rownorm_fp8<<<2 * NROW / 4, 256, 0, stream>>>(fm_t, fm_s, nt, ns);
  gram_kernel<<<NBLK, 256, 0, stream>>>(nt, ns, partials);
  reduce_partials<<<1, 256, 0, stream>>>(partials, out);
}